// Round 17
// baseline (1740.332 us; speedup 1.0000x reference)
//
#include <hip/hip_runtime.h>

typedef _Float16 half2_v __attribute__((ext_vector_type(2)));
typedef unsigned int u32;

// ---------------- ws layout ----------------
// u32 offsets (packed weights)
#define W2K_O    0         // [8 mm][128 p][16 kl]  h2 pairs of W2h k-slice
#define WHHP_O   16384     // [8][96 o][128 k]  h2
#define WIHP_O   114688    // [8][96 o][256 k]  h2
#define NPACKW   311296
// byte offsets
#define S2P_B    1245184   // [32][64 j][128 p] f16
#define S2T_B    1769472   // [32][256 d][64 j] f16 (seq2 transposed)
#define M1_B     2818048   // [32][512 o][64 j] f16  (Wg_att . seq2^T)
#define PROJX_B  4915200   // [32*256][128] f16
#define GATEX_B  7012352   // [32*256][512] f16
#define EXCH_B   15400960  // [32][2048] u32 : [0..1023] php[p][mm], [1024..1279] h, [1280..1791] ip

#define SMEM_BYTES 149648

__device__ __forceinline__ float fdot2(half2_v a, half2_v b, float c) {
    return __builtin_amdgcn_fdot2(a, b, c, false);
}
__device__ __forceinline__ half2_v h2_of(u32 u) { return __builtin_bit_cast(half2_v, u); }
__device__ __forceinline__ u32 pack_h2(float a, float b) {
    half2_v r; r[0] = (_Float16)a; r[1] = (_Float16)b;
    return __builtin_bit_cast(u32, r);
}
__device__ __forceinline__ float dot4(uint4 w, uint4 a, float acc) {
    acc = fdot2(h2_of(w.x), h2_of(a.x), acc);
    acc = fdot2(h2_of(w.y), h2_of(a.y), acc);
    acc = fdot2(h2_of(w.z), h2_of(a.z), acc);
    acc = fdot2(h2_of(w.w), h2_of(a.w), acc);
    return acc;
}
__device__ __forceinline__ float fast_tanh(float x) {
    float e = __expf(2.0f * x);
    return 1.0f - 2.0f / (e + 1.0f);
}
__device__ __forceinline__ float fast_sigmoid(float x) {
    return 1.0f / (1.0f + __expf(-x));
}
__device__ __forceinline__ u32 aload(const u32* p) {
    return __hip_atomic_load(p, __ATOMIC_RELAXED, __HIP_MEMORY_SCOPE_AGENT);
}
__device__ __forceinline__ void astore(u32* p, u32 v) {
    __hip_atomic_store(p, v, __ATOMIC_RELAXED, __HIP_MEMORY_SCOPE_AGENT);
}
__device__ __forceinline__ u32 mkw(float x, u32 st) {
    unsigned short hb = __builtin_bit_cast(unsigned short, (_Float16)x);
    return (st << 16) | (u32)hb;
}
__device__ __forceinline__ float f16low(u32 v) {
    return (float)__builtin_bit_cast(_Float16, (unsigned short)(v & 0xFFFFu));
}

// ---------------- prep kernels ----------------
__global__ void prep_pack_w(const float* __restrict__ W2, const float* __restrict__ wih,
                            const float* __restrict__ whh, u32* __restrict__ ws_u) {
    int idx = blockIdx.x * 256 + threadIdx.x;
    if (idx >= NPACKW) return;
    float a, c;
    if (idx < WHHP_O) {                       // W2h k-slice: [mm][p128][kl16]
        int mm = idx >> 11, r = idx & 2047, p = r >> 4, kl = r & 15;
        int row = 256 + mm * 32 + 2 * kl;
        a = W2[row * 128 + p]; c = W2[(row + 1) * 128 + p];
    } else if (idx < WIHP_O) {                // whh: [mm][o96][k128]
        int t2 = idx - WHHP_O, mm = t2 / 12288, r = t2 % 12288, o = r >> 7, k = r & 127;
        int row = (o >> 5) * 256 + mm * 32 + (o & 31);
        a = whh[row * 256 + 2 * k]; c = whh[row * 256 + 2 * k + 1];
    } else {                                  // wih: [mm][o96][k256]
        int t2 = idx - WIHP_O, mm = t2 / 24576, r = t2 % 24576, o = r >> 8, k = r & 255;
        int row = (o >> 5) * 256 + mm * 32 + (o & 31);
        a = wih[row * 512 + 2 * k]; c = wih[row * 512 + 2 * k + 1];
    }
    ws_u[idx] = pack_h2(a, c);
}

__global__ void prep_s2p(const float* __restrict__ seq2, const float* __restrict__ W1,
                         _Float16* __restrict__ outh) {
    int idx = blockIdx.x * 256 + threadIdx.x;   // 262144
    int p = idx & 127, j = (idx >> 7) & 63, b = idx >> 13;
    const float* s2 = seq2 + (b * 64 + j) * 256;
    float acc = 0.f;
    #pragma unroll 8
    for (int d = 0; d < 256; ++d) acc += s2[d] * W1[d * 128 + p];
    outh[idx] = (_Float16)acc;
}

__global__ void prep_s2T(const float* __restrict__ seq2, _Float16* __restrict__ dst) {
    int idx = blockIdx.x * 256 + threadIdx.x;   // 524288 : [b][d][j]
    int j = idx & 63, d = (idx >> 6) & 255, b = idx >> 14;
    dst[idx] = (_Float16)seq2[(b * 64 + j) * 256 + d];
}

__global__ void prep_m1(const float* __restrict__ Wg, const float* __restrict__ seq2,
                        _Float16* __restrict__ dst) {
    int idx = blockIdx.x * 256 + threadIdx.x;   // 1048576 : [b][o][j]
    int j = idx & 63, o = (idx >> 6) & 511, b = idx >> 15;
    const float* wr = Wg + o * 512 + 256;
    const float* s2 = seq2 + (b * 64 + j) * 256;
    float acc = 0.f;
    #pragma unroll 8
    for (int d = 0; d < 256; ++d) acc += wr[d] * s2[d];
    dst[idx] = (_Float16)acc;
}

// C[8192][N] = A[8192][256] @ B ; mode0: B[k][n]=Bsrc[k*N+n] ; mode1: B[k][n]=Bsrc[n*512+k]
__global__ void prep_gemm(const float* __restrict__ A, const float* __restrict__ Bsrc,
                          int mode, _Float16* __restrict__ C, int N) {
    __shared__ float As[64][17];
    __shared__ float Bs[16][65];
    int r0 = blockIdx.x * 64, n0 = blockIdx.y * 64;
    int tid = threadIdx.x;
    int tr = tid >> 4, tc = tid & 15;
    float acc[4][4] = {};
    for (int k0 = 0; k0 < 256; k0 += 16) {
        #pragma unroll
        for (int i = 0; i < 4; ++i) {
            int rr = (tid >> 4) + i * 16, kk = tid & 15;
            As[rr][kk] = A[(r0 + rr) * 256 + k0 + kk];
        }
        #pragma unroll
        for (int i = 0; i < 4; ++i) {
            if (mode == 0) { int kk = (tid >> 6) + i * 4, nn = tid & 63; Bs[kk][nn] = Bsrc[(k0 + kk) * N + n0 + nn]; }
            else           { int nn = (tid >> 4) + i * 16, kk = tid & 15; Bs[kk][nn] = Bsrc[(n0 + nn) * 512 + k0 + kk]; }
        }
        __syncthreads();
        #pragma unroll
        for (int k = 0; k < 16; ++k)
            #pragma unroll
            for (int i = 0; i < 4; ++i)
                #pragma unroll
                for (int j = 0; j < 4; ++j)
                    acc[i][j] += As[tr * 4 + i][k] * Bs[k][tc * 4 + j];
        __syncthreads();
    }
    for (int i = 0; i < 4; ++i)
        for (int j = 0; j < 4; ++j)
            C[(size_t)(r0 + tr * 4 + i) * N + n0 + tc * 4 + j] = (_Float16)acc[i][j];
}

// ---------------- main persistent kernel ----------------
__global__ void __launch_bounds__(1024) match_rnn(
    const float* __restrict__ seq1, const float* __restrict__ mask1,
    const float* __restrict__ mask2, const float* __restrict__ v,
    const float* __restrict__ bg, const float* __restrict__ bih,
    const float* __restrict__ bhh, char* __restrict__ ws, float* __restrict__ out)
{
    const int m = blockIdx.x >> 5;      // group member 0..7
    const int b = blockIdx.x & 31;      // batch / group id
    const int tid = threadIdx.x;

    extern __shared__ char smem[];
    u32* s_whh4 = (u32*)smem;                      // 12288 (read-order uint4 layout)
    u32* s_wih4 = s_whh4 + 12288;                  // 12288
    u32* s_w2k  = s_wih4 + 12288;                  // [128 p][17]
    u32* s_s2pU = s_w2k + 2176;                    // 4608 ([64][144] f16)
    u32* s_m1u  = s_s2pU + 4608;                   // [64 o][33]
    u32* s_s2Tu = s_m1u + 2112;                    // [64 d][33]
    float* s_redA = (float*)(s_s2Tu + 2112);       // [96] gh sums (+bhh)
    float* s_redD = s_redA + 96;                   // [96] gi sums (+bih)
    u32* s_h2u  = (u32*)(s_redD + 96);             // [160] padded h pairs
    u32* s_ip2a = s_h2u + 160;                     // [160]
    u32* s_ip2b = s_ip2a + 160;                    // [160]
    float* s_projh = (float*)(s_ip2b + 160);       // [144] padded stride-9/8
    float* s_projx = s_projh + 144;                // [144] padded
    float* s_v   = s_projx + 144;                  // [144] padded
    float* s_w   = s_v + 144;                      // [64]
    u32* s_wp   = (u32*)(s_w + 64);                // [32] packed softmax pairs
    float* s_neg = (float*)(s_wp + 32);            // [64]
    float* s_gx  = s_neg + 64;                     // [64]
    float* s_xc  = s_gx + 64;                      // [64]
    float* s_bg  = s_xc + 64;                      // [64]
    float* s_bih = s_bg + 64;                      // [96]
    float* s_bhh = s_bih + 96;                     // [96]
    float* s_hf  = s_bhh + 96;                     // [32]
    u32* s_hloc  = (u32*)(s_hf + 32);              // [16]
    float* s_m1v = (float*)(s_hloc + 16);          // [4]

    unsigned short* s_s2p  = (unsigned short*)s_s2pU;
    unsigned short* s_h2h  = (unsigned short*)s_h2u;
    unsigned short* s_ip2ah = (unsigned short*)s_ip2a;
    unsigned short* s_ip2bh = (unsigned short*)s_ip2b;

    const u32* wsrc = (const u32*)ws;

    // ---- stage weights: read-order layout (wave,c,lane) -> lane-contiguous b128 ----
    for (int i = tid; i < 12288; i += 1024) {     // whh
        int o = i >> 7, k = i & 127, u = k >> 2;
        int du4 = ((o >> 3) * 256) + ((u & 3) * 64) + (((o & 7) << 3) | (u >> 2));
        s_whh4[du4 * 4 + (k & 3)] = wsrc[WHHP_O + m * 12288 + i];
    }
    for (int i = tid; i < 12288; i += 1024) {     // wih K-low (pairs 0..127)
        int o = i >> 7, k = i & 127, u = k >> 2;
        int du4 = ((o >> 3) * 256) + ((u & 3) * 64) + (((o & 7) << 3) | (u >> 2));
        s_wih4[du4 * 4 + (k & 3)] = wsrc[WIHP_O + m * 24576 + o * 256 + k];
    }
    for (int i = tid; i < 2048; i += 1024) {      // W2h k-slice
        int p = i >> 4, kl = i & 15;
        s_w2k[p * 17 + kl] = wsrc[W2K_O + m * 2048 + i];
    }
    {
        const u32* s2src = wsrc + (S2P_B / 4) + b * 4096;
        for (int i = tid; i < 4096; i += 1024) {
            int j = i >> 6, kk = i & 63;
            s_s2pU[j * 72 + kk] = s2src[i];
        }
        const u32* m1src = wsrc + (M1_B / 4) + (b * 512 + m * 64) * 32;
        for (int i = tid; i < 2048; i += 1024) {
            int o = i >> 5, jw = i & 31;
            s_m1u[o * 33 + jw] = m1src[i];
        }
        if (m >= 4) {
            const u32* stsrc = wsrc + (S2T_B / 4) + (b * 256 + (m - 4) * 64) * 32;
            for (int i = tid; i < 2048; i += 1024) {
                int dd = i >> 5, jw = i & 31;
                s_s2Tu[dd * 33 + jw] = stsrc[i];
            }
        } else {
            for (int i = tid; i < 2112; i += 1024) s_s2Tu[i] = 0u;
        }
    }
    if (tid < 128) s_v[tid + (tid >> 3)] = v[tid];
    if (tid < 64) { s_neg[tid] = (mask2[b * 64 + tid] > 0.f) ? 0.f : -1e9f; s_bg[tid] = bg[m * 64 + tid]; }
    if (tid < 96) {
        int row = (tid >> 5) * 256 + m * 32 + (tid & 31);
        s_bih[tid] = bih[row]; s_bhh[tid] = bhh[row];
    }
    if (tid < 32) s_hf[tid] = 0.f;

    // persistent register weights: wih K-high (pairs 128..255)
    uint4 wiA = {}, wiB = {}, wiC = {}, wiD = {};
    const int oAD = ((tid >> 6) << 3) + ((tid & 63) >> 3);   // wave*8 + (l>>3)
    const int ksAD = tid & 7;
    if (tid < 768) {
        const uint4* wip = (const uint4*)(wsrc + WIHP_O + m * 24576 + oAD * 256 + 128 + ksAD * 16);
        wiA = wip[0]; wiB = wip[1]; wiC = wip[2]; wiD = wip[3];
    }

    u32* exch = (u32*)(ws + EXCH_B) + b * 2048;
    const u32* g_projx = (const u32*)(ws + PROJX_B);
    const u32* g_gatex = (const u32*)(ws + GATEX_B);

    int dead = 0;
    __syncthreads();

    for (int t = 0; t < 256; ++t) {
        const u32 st = (u32)(t + 1);
        // ---- issue prefetch loads (lanes 896+) ----
        float4 xv = {};
        u32 pxv = 0, gxv = 0; float mkv = 0.f;
        if (tid >= 896 && tid < 912) {
            if (m < 4)
                xv = ((const float4*)(seq1 + (size_t)(b * 256 + t) * 256 + m * 64))[tid - 896];
        } else if (tid >= 912 && tid < 976)
            pxv = g_projx[(b * 256 + t) * 64 + (tid - 912)];
        else if (tid >= 976 && tid < 1008)
            gxv = g_gatex[(b * 256 + t) * 256 + m * 32 + (tid - 976)];
        else if (tid == 1008)
            mkv = mask1[b * 256 + t];

        // ---- poll {php[p][mm], h} from prev step (stamp == t) ----
        if (t > 0) {
            u32 v1, v2;
            const bool p2 = tid < 256;
            const u32 stp = (u32)t;
            if (!dead) {
                int sp = 0;
                for (;;) {
                    v1 = aload(exch + tid);
                    v2 = p2 ? aload(exch + 1024 + tid) : (stp << 16);
                    bool ok = ((v1 >> 16) == stp) && ((v2 >> 16) == stp);
                    if (__all((int)ok)) break;
                    __builtin_amdgcn_s_sleep(1);
                    if (++sp > (1 << 17)) { dead = 1; break; }
                }
            } else { v1 = aload(exch + tid); v2 = p2 ? aload(exch + 1024 + tid) : 0; }
            // php: 8 member-partials of one p in 8 consecutive lanes -> shfl sum
            float ph = f16low(v1);
            ph += __shfl_down(ph, 4, 8);
            ph += __shfl_down(ph, 2, 8);
            ph += __shfl_down(ph, 1, 8);
            if ((tid & 7) == 0) { int p = tid >> 3; s_projh[p + (p >> 3)] = ph; }
            if (p2) {
                int k = tid;
                int pos = ((k >> 5) * 20 + ((k >> 1) & 15)) * 2 + (k & 1);
                s_h2h[pos] = (unsigned short)(v2 & 0xFFFFu);
            }
        } else {
            if (tid < 160) s_h2u[tid] = 0u;
            if (tid < 144) s_projh[tid] = 0.f;
        }
        // ---- prefetch stores (same phase, after per-wave poll exit) ----
        if (tid >= 896 && tid < 912) {
            int q = tid - 896;
            s_xc[4 * q] = xv.x; s_xc[4 * q + 1] = xv.y; s_xc[4 * q + 2] = xv.z; s_xc[4 * q + 3] = xv.w;
        } else if (tid >= 912 && tid < 976) {
            half2_v h = h2_of(pxv); int i = tid - 912;
            int base = 2 * i + (i >> 2);
            s_projx[base] = (float)h[0]; s_projx[base + 1] = (float)h[1];
        } else if (tid >= 976 && tid < 1008) {
            half2_v h = h2_of(gxv); int i = tid - 976;
            s_gx[2 * i] = (float)h[0]; s_gx[2 * i + 1] = (float)h[1];
        } else if (tid == 1008) s_m1v[0] = mkv;
        __syncthreads();                                    // sync 1

        // ---- B: scores (all lanes; 16-lane rows; padded conflict-free reads) ----
        {
            int j = tid >> 4, pk = tid & 15, p0 = pk * 8, pb = pk * 9;
            uint4 sv = *(const uint4*)&s_s2p[j * 144 + p0];
            const u32* su = (const u32*)&sv;
            float acc = 0.f;
            #pragma unroll
            for (int q = 0; q < 4; ++q) {
                half2_v h = h2_of(su[q]);
                int pc = pb + 2 * q;
                float a0 = (float)h[0] + s_projx[pc] + s_projh[pc];
                float a1 = (float)h[1] + s_projx[pc + 1] + s_projh[pc + 1];
                acc += fast_tanh(a0) * s_v[pc];
                acc += fast_tanh(a1) * s_v[pc + 1];
            }
            acc += __shfl_down(acc, 8, 16);
            acc += __shfl_down(acc, 4, 16);
            acc += __shfl_down(acc, 2, 16);
            acc += __shfl_down(acc, 1, 16);
            if (pk == 0) s_w[j] = acc + s_neg[j];
        }
        __syncthreads();                                    // sync 2

        // ---- softmax replicated in waves 0-7 (each wave writes identical s_wp;
        //      its own C' reads are in-wave ordered -> no barrier needed) ----
        if (tid < 512) {
            int lane = tid & 63;
            float sc = s_w[lane], mx = sc;
            #pragma unroll
            for (int off = 32; off > 0; off >>= 1) mx = fmaxf(mx, __shfl_xor(mx, off));
            float e = __expf(sc - mx), s = e;
            #pragma unroll
            for (int off = 32; off > 0; off >>= 1) s += __shfl_xor(s, off);
            float wv = e / s;
            float nb = __shfl_down(wv, 1);
            if (!(lane & 1)) s_wp[lane >> 1] = pack_h2(wv, nb);
        }

        // ---- C' fused: 8-lane group per o; lanes 0-3 gate(M1), 4-7 att(s2T); packed-w fdot2 ----
        if (tid < 512) {
            int o = tid >> 3, r = tid & 7, q = r & 3;
            const u32* src = (r >= 4) ? &s_s2Tu[o * 33] : &s_m1u[o * 33];
            float acc = 0.f;
            #pragma unroll
            for (int c = 0; c < 8; ++c)
                acc = fdot2(h2_of(src[q * 8 + c]), h2_of(s_wp[q * 8 + c]), acc);
            acc += __shfl_down(acc, 2, 4);
            acc += __shfl_down(acc, 1, 4);
            float attv = __shfl_down(acc, 4, 8);   // lane r=0 gets lane r=4's att sum
            if (r == 0) {
                float g = acc + s_gx[o] + s_bg[o];
                float inpv = (m < 4) ? s_xc[o] : attv;
                astore(&exch[1280 + m * 64 + o], mkw(fast_sigmoid(g) * inpv, st));
            }
        }
        // ---- phase A: gh partials (in the ip-RTT shadow; threads 0..767) ----
        if (tid < 768) {
            const uint4* wbase = (const uint4*)s_whh4 + (tid >> 6) * 256;
            float acc = 0.f;
            #pragma unroll
            for (int c = 0; c < 4; ++c) {
                uint4 wv4 = wbase[c * 64 + (tid & 63)];
                uint4 av = *(const uint4*)&s_h2u[ksAD * 20 + c * 4];
                acc = dot4(wv4, av, acc);
            }
            acc += __shfl_down(acc, 4, 8);
            acc += __shfl_down(acc, 2, 8);
            acc += __shfl_down(acc, 1, 8);
            if (ksAD == 0) s_redA[oAD] = acc + s_bhh[oAD];
        }
        // ---- poll ip (512 words, stamp == st) ----
        if (tid < 512) {
            u32 vv;
            if (!dead) {
                int sp = 0;
                for (;;) {
                    vv = aload(exch + 1280 + tid);
                    if (__all((int)((vv >> 16) == st))) break;
                    __builtin_amdgcn_s_sleep(1);
                    if (++sp > (1 << 17)) { dead = 1; break; }
                }
            } else vv = aload(exch + 1280 + tid);
            int i = tid;
            if (i < 256) {
                int pos = ((i >> 5) * 20 + ((i >> 1) & 15)) * 2 + (i & 1);
                s_ip2ah[pos] = (unsigned short)(vv & 0xFFFFu);
            } else {
                int i2 = i - 256;
                int pos = ((i2 >> 5) * 20 + ((i2 >> 1) & 15)) * 2 + (i2 & 1);
                s_ip2bh[pos] = (unsigned short)(vv & 0xFFFFu);
            }
        }
        __syncthreads();                                    // sync 4

        // ---- phase D: gi partials (shfl-reduced, bias folded) ----
        if (tid < 768) {
            const uint4* wbase = (const uint4*)s_wih4 + (tid >> 6) * 256;
            float acc = 0.f;
            #pragma unroll
            for (int c = 0; c < 4; ++c) {
                uint4 wv4 = wbase[c * 64 + (tid & 63)];
                uint4 av = *(const uint4*)&s_ip2a[ksAD * 20 + c * 4];
                acc = dot4(wv4, av, acc);
            }
            acc = dot4(wiA, *(const uint4*)&s_ip2b[ksAD * 20 + 0],  acc);
            acc = dot4(wiB, *(const uint4*)&s_ip2b[ksAD * 20 + 4],  acc);
            acc = dot4(wiC, *(const uint4*)&s_ip2b[ksAD * 20 + 8],  acc);
            acc = dot4(wiD, *(const uint4*)&s_ip2b[ksAD * 20 + 12], acc);
            acc += __shfl_down(acc, 4, 8);
            acc += __shfl_down(acc, 2, 8);
            acc += __shfl_down(acc, 1, 8);
            if (ksAD == 0) s_redD[oAD] = acc + s_bih[oAD];
        }
        __syncthreads();                                    // sync 5

        // ---- GRU elementwise + h publish + php (all wave 0; in-wave LDS ordering) ----
        if (tid < 64) {
            if (tid < 32) {
                int o = tid;
                float r_ = fast_sigmoid(s_redD[o] + s_redA[o]);
                float z_ = fast_sigmoid(s_redD[32 + o] + s_redA[32 + o]);
                float n_ = fast_tanh(s_redD[64 + o] + r_ * s_redA[64 + o]);
                float hn = (1.f - z_) * n_ + z_ * s_hf[o];
                s_hf[o] = hn;
                out[(size_t)(b * 256 + t) * 256 + m * 32 + o] = hn * s_m1v[0];
                astore(&exch[1024 + m * 32 + o], mkw(hn, st));
                float nb = __shfl_down(hn, 1);
                if (!(o & 1)) s_hloc[o >> 1] = pack_h2(hn, nb);
            }
            // php partials from own new h-slice (lanes 0-63; same wave as s_hloc writers)
            int p = tid;
            float a0 = 0.f, a1 = 0.f;
            #pragma unroll
            for (int cc = 0; cc < 16; ++cc) {
                u32 hp = s_hloc[cc];
                a0 = fdot2(h2_of(s_w2k[p * 17 + cc]), h2_of(hp), a0);
                a1 = fdot2(h2_of(s_w2k[(p + 64) * 17 + cc]), h2_of(hp), a1);
            }
            astore(&exch[p * 8 + m], mkw(a0, st));
            astore(&exch[(p + 64) * 8 + m], mkw(a1, st));
        }
        // no trailing sync: next-iteration polls gate on stamps
    }
}

extern "C" void kernel_launch(void* const* d_in, const int* in_sizes, int n_in,
                              void* d_out, int out_size, void* d_ws, size_t ws_size,
                              hipStream_t stream) {
    const float* seq1  = (const float*)d_in[0];
    const float* seq2  = (const float*)d_in[1];
    const float* mask1 = (const float*)d_in[2];
    const float* mask2 = (const float*)d_in[3];
    const float* W1    = (const float*)d_in[4];
    const float* W2    = (const float*)d_in[5];
    const float* v     = (const float*)d_in[6];
    const float* Wg    = (const float*)d_in[7];
    const float* bg    = (const float*)d_in[8];
    const float* wih   = (const float*)d_in[9];
    const float* whh   = (const float*)d_in[10];
    const float* bih   = (const float*)d_in[11];
    const float* bhh   = (const float*)d_in[12];

    char* ws = (char*)d_ws;

    (void)hipFuncSetAttribute(reinterpret_cast<const void*>(match_rnn),
                              hipFuncAttributeMaxDynamicSharedMemorySize, SMEM_BYTES);

    prep_pack_w<<<dim3((NPACKW + 255) / 256), dim3(256), 0, stream>>>(W2, wih, whh, (u32*)ws);
    prep_s2p<<<dim3(1024), dim3(256), 0, stream>>>(seq2, W1, (_Float16*)(ws + S2P_B));
    prep_s2T<<<dim3(2048), dim3(256), 0, stream>>>(seq2, (_Float16*)(ws + S2T_B));
    prep_m1<<<dim3(4096), dim3(256), 0, stream>>>(Wg, seq2, (_Float16*)(ws + M1_B));
    prep_gemm<<<dim3(128, 2), dim3(256), 0, stream>>>(seq1, W2, 0, (_Float16*)(ws + PROJX_B), 128);
    prep_gemm<<<dim3(128, 8), dim3(256), 0, stream>>>(seq1, Wg, 1, (_Float16*)(ws + GATEX_B), 512);
    (void)hipMemsetAsync(ws + EXCH_B, 0, 262144, stream);
    match_rnn<<<dim3(256), dim3(1024), SMEM_BYTES, stream>>>(seq1, mask1, mask2, v, bg, bih, bhh, ws, (float*)d_out);
}

// Round 18
// 1523.626 us; speedup vs baseline: 1.1422x; 1.1422x over previous
//
#include <hip/hip_runtime.h>

typedef _Float16 half2_v __attribute__((ext_vector_type(2)));
typedef unsigned int u32;
typedef unsigned long long u64;

// ---------------- ws layout ----------------
// u32 offsets (packed weights)
#define W2K_O    0         // [8 mm][128 p][16 kl]  h2 pairs of W2h k-slice
#define WHHP_O   16384     // [8][96 o][128 k]  h2
#define WIHP_O   114688    // [8][96 o][256 k]  h2
#define NPACKW   311296
// byte offsets
#define S2P_B    1245184   // [32][64 j][128 p] f16
#define S2T_B    1769472   // [32][256 d][64 j] f16 (seq2 transposed)
#define M1_B     2818048   // [32][512 o][64 j] f16  (Wg_att . seq2^T)
#define PROJX_B  4915200   // [32*256][128] f16
#define GATEX_B  7012352   // [32*256][512] f16
#define EXCH_B   15400960  // [32][1024] u64 : [0..511] php pairs, [512..639] h pairs, [640..895] ip pairs

#define SMEM_BYTES 149648

__device__ __forceinline__ float fdot2(half2_v a, half2_v b, float c) {
    return __builtin_amdgcn_fdot2(a, b, c, false);
}
__device__ __forceinline__ half2_v h2_of(u32 u) { return __builtin_bit_cast(half2_v, u); }
__device__ __forceinline__ u32 pack_h2(float a, float b) {
    half2_v r; r[0] = (_Float16)a; r[1] = (_Float16)b;
    return __builtin_bit_cast(u32, r);
}
__device__ __forceinline__ float dot4(uint4 w, uint4 a, float acc) {
    acc = fdot2(h2_of(w.x), h2_of(a.x), acc);
    acc = fdot2(h2_of(w.y), h2_of(a.y), acc);
    acc = fdot2(h2_of(w.z), h2_of(a.z), acc);
    acc = fdot2(h2_of(w.w), h2_of(a.w), acc);
    return acc;
}
__device__ __forceinline__ float fast_tanh(float x) {
    float e = __expf(2.0f * x);
    return 1.0f - 2.0f / (e + 1.0f);
}
__device__ __forceinline__ float fast_sigmoid(float x) {
    return 1.0f / (1.0f + __expf(-x));
}
__device__ __forceinline__ u64 aload64(const u64* p) {
    return __hip_atomic_load(p, __ATOMIC_RELAXED, __HIP_MEMORY_SCOPE_AGENT);
}
__device__ __forceinline__ void astore64(u64* p, u64 v) {
    __hip_atomic_store(p, v, __ATOMIC_RELAXED, __HIP_MEMORY_SCOPE_AGENT);
}
__device__ __forceinline__ u32 mkw(float x, u32 st) {
    unsigned short hb = __builtin_bit_cast(unsigned short, (_Float16)x);
    return (st << 16) | (u32)hb;
}
__device__ __forceinline__ u64 mkw64(float a, float b, u32 st) {
    return (u64)mkw(a, st) | ((u64)mkw(b, st) << 32);
}
__device__ __forceinline__ float f16low(u32 v) {
    return (float)__builtin_bit_cast(_Float16, (unsigned short)(v & 0xFFFFu));
}

// ---------------- prep kernels ----------------
__global__ void prep_pack_w(const float* __restrict__ W2, const float* __restrict__ wih,
                            const float* __restrict__ whh, u32* __restrict__ ws_u) {
    int idx = blockIdx.x * 256 + threadIdx.x;
    if (idx >= NPACKW) return;
    float a, c;
    if (idx < WHHP_O) {                       // W2h k-slice: [mm][p128][kl16]
        int mm = idx >> 11, r = idx & 2047, p = r >> 4, kl = r & 15;
        int row = 256 + mm * 32 + 2 * kl;
        a = W2[row * 128 + p]; c = W2[(row + 1) * 128 + p];
    } else if (idx < WIHP_O) {                // whh: [mm][o96][k128]
        int t2 = idx - WHHP_O, mm = t2 / 12288, r = t2 % 12288, o = r >> 7, k = r & 127;
        int row = (o >> 5) * 256 + mm * 32 + (o & 31);
        a = whh[row * 256 + 2 * k]; c = whh[row * 256 + 2 * k + 1];
    } else {                                  // wih: [mm][o96][k256]
        int t2 = idx - WIHP_O, mm = t2 / 24576, r = t2 % 24576, o = r >> 8, k = r & 255;
        int row = (o >> 5) * 256 + mm * 32 + (o & 31);
        a = wih[row * 512 + 2 * k]; c = wih[row * 512 + 2 * k + 1];
    }
    ws_u[idx] = pack_h2(a, c);
}

__global__ void prep_s2p(const float* __restrict__ seq2, const float* __restrict__ W1,
                         _Float16* __restrict__ outh) {
    int idx = blockIdx.x * 256 + threadIdx.x;   // 262144
    int p = idx & 127, j = (idx >> 7) & 63, b = idx >> 13;
    const float* s2 = seq2 + (b * 64 + j) * 256;
    float acc = 0.f;
    #pragma unroll 8
    for (int d = 0; d < 256; ++d) acc += s2[d] * W1[d * 128 + p];
    outh[idx] = (_Float16)acc;
}

__global__ void prep_s2T(const float* __restrict__ seq2, _Float16* __restrict__ dst) {
    int idx = blockIdx.x * 256 + threadIdx.x;   // 524288 : [b][d][j]
    int j = idx & 63, d = (idx >> 6) & 255, b = idx >> 14;
    dst[idx] = (_Float16)seq2[(b * 64 + j) * 256 + d];
}

__global__ void prep_m1(const float* __restrict__ Wg, const float* __restrict__ seq2,
                        _Float16* __restrict__ dst) {
    int idx = blockIdx.x * 256 + threadIdx.x;   // 1048576 : [b][o][j]
    int j = idx & 63, o = (idx >> 6) & 511, b = idx >> 15;
    const float* wr = Wg + o * 512 + 256;
    const float* s2 = seq2 + (b * 64 + j) * 256;
    float acc = 0.f;
    #pragma unroll 8
    for (int d = 0; d < 256; ++d) acc += wr[d] * s2[d];
    dst[idx] = (_Float16)acc;
}

// C[8192][N] = A[8192][256] @ B ; mode0: B[k][n]=Bsrc[k*N+n] ; mode1: B[k][n]=Bsrc[n*512+k]
__global__ void prep_gemm(const float* __restrict__ A, const float* __restrict__ Bsrc,
                          int mode, _Float16* __restrict__ C, int N) {
    __shared__ float As[64][17];
    __shared__ float Bs[16][65];
    int r0 = blockIdx.x * 64, n0 = blockIdx.y * 64;
    int tid = threadIdx.x;
    int tr = tid >> 4, tc = tid & 15;
    float acc[4][4] = {};
    for (int k0 = 0; k0 < 256; k0 += 16) {
        #pragma unroll
        for (int i = 0; i < 4; ++i) {
            int rr = (tid >> 4) + i * 16, kk = tid & 15;
            As[rr][kk] = A[(r0 + rr) * 256 + k0 + kk];
        }
        #pragma unroll
        for (int i = 0; i < 4; ++i) {
            if (mode == 0) { int kk = (tid >> 6) + i * 4, nn = tid & 63; Bs[kk][nn] = Bsrc[(k0 + kk) * N + n0 + nn]; }
            else           { int nn = (tid >> 4) + i * 16, kk = tid & 15; Bs[kk][nn] = Bsrc[(n0 + nn) * 512 + k0 + kk]; }
        }
        __syncthreads();
        #pragma unroll
        for (int k = 0; k < 16; ++k)
            #pragma unroll
            for (int i = 0; i < 4; ++i)
                #pragma unroll
                for (int j = 0; j < 4; ++j)
                    acc[i][j] += As[tr * 4 + i][k] * Bs[k][tc * 4 + j];
        __syncthreads();
    }
    for (int i = 0; i < 4; ++i)
        for (int j = 0; j < 4; ++j)
            C[(size_t)(r0 + tr * 4 + i) * N + n0 + tc * 4 + j] = (_Float16)acc[i][j];
}

// ---------------- main persistent kernel ----------------
__global__ void __launch_bounds__(1024) match_rnn(
    const float* __restrict__ seq1, const float* __restrict__ mask1,
    const float* __restrict__ mask2, const float* __restrict__ v,
    const float* __restrict__ bg, const float* __restrict__ bih,
    const float* __restrict__ bhh, char* __restrict__ ws, float* __restrict__ out)
{
    const int m = blockIdx.x >> 5;      // group member 0..7
    const int b = blockIdx.x & 31;      // batch / group id
    const int tid = threadIdx.x;

    extern __shared__ char smem[];
    u32* s_whh4 = (u32*)smem;                      // 12288 (read-order uint4 layout)
    u32* s_wih4 = s_whh4 + 12288;                  // 12288
    u32* s_w2k  = s_wih4 + 12288;                  // [128 p][17]
    u32* s_s2pU = s_w2k + 2176;                    // 4608 ([64][144] f16)
    u32* s_m1u  = s_s2pU + 4608;                   // [64 o][33]
    u32* s_s2Tu = s_m1u + 2112;                    // [64 d][33]
    float* s_redA = (float*)(s_s2Tu + 2112);       // [96] gh sums (+bhh)
    float* s_redD = s_redA + 96;                   // [96] gi sums (+bih)
    u32* s_h2u  = (u32*)(s_redD + 96);             // [160] padded h pairs
    u32* s_ip2a = s_h2u + 160;                     // [160]
    u32* s_ip2b = s_ip2a + 160;                    // [160]
    float* s_projh = (float*)(s_ip2b + 160);       // [144] padded stride-9/8
    float* s_projx = s_projh + 144;                // [144] padded
    float* s_v   = s_projx + 144;                  // [144] padded
    float* s_w   = s_v + 144;                      // [64]
    u32* s_wp   = (u32*)(s_w + 64);                // [32] packed softmax pairs
    float* s_neg = (float*)(s_wp + 32);            // [64]
    float* s_gx  = s_neg + 64;                     // [64]
    float* s_xc  = s_gx + 64;                      // [64]
    float* s_bg  = s_xc + 64;                      // [64]
    float* s_bih = s_bg + 64;                      // [96]
    float* s_bhh = s_bih + 96;                     // [96]
    float* s_hf  = s_bhh + 96;                     // [32]
    u32* s_hloc  = (u32*)(s_hf + 32);              // [16]
    float* s_m1v = (float*)(s_hloc + 16);          // [4]

    unsigned short* s_s2p  = (unsigned short*)s_s2pU;

    const u32* wsrc = (const u32*)ws;

    // ---- stage weights: read-order layout (wave,c,lane) -> lane-contiguous b128 ----
    for (int i = tid; i < 12288; i += 1024) {     // whh
        int o = i >> 7, k = i & 127, u = k >> 2;
        int du4 = ((o >> 3) * 256) + ((u & 3) * 64) + (((o & 7) << 3) | (u >> 2));
        s_whh4[du4 * 4 + (k & 3)] = wsrc[WHHP_O + m * 12288 + i];
    }
    for (int i = tid; i < 12288; i += 1024) {     // wih K-low (pairs 0..127)
        int o = i >> 7, k = i & 127, u = k >> 2;
        int du4 = ((o >> 3) * 256) + ((u & 3) * 64) + (((o & 7) << 3) | (u >> 2));
        s_wih4[du4 * 4 + (k & 3)] = wsrc[WIHP_O + m * 24576 + o * 256 + k];
    }
    for (int i = tid; i < 2048; i += 1024) {      // W2h k-slice
        int p = i >> 4, kl = i & 15;
        s_w2k[p * 17 + kl] = wsrc[W2K_O + m * 2048 + i];
    }
    {
        const u32* s2src = wsrc + (S2P_B / 4) + b * 4096;
        for (int i = tid; i < 4096; i += 1024) {
            int j = i >> 6, kk = i & 63;
            s_s2pU[j * 72 + kk] = s2src[i];
        }
        const u32* m1src = wsrc + (M1_B / 4) + (b * 512 + m * 64) * 32;
        for (int i = tid; i < 2048; i += 1024) {
            int o = i >> 5, jw = i & 31;
            s_m1u[o * 33 + jw] = m1src[i];
        }
        if (m >= 4) {
            const u32* stsrc = wsrc + (S2T_B / 4) + (b * 256 + (m - 4) * 64) * 32;
            for (int i = tid; i < 2048; i += 1024) {
                int dd = i >> 5, jw = i & 31;
                s_s2Tu[dd * 33 + jw] = stsrc[i];
            }
        } else {
            for (int i = tid; i < 2112; i += 1024) s_s2Tu[i] = 0u;
        }
    }
    if (tid < 128) s_v[tid + (tid >> 3)] = v[tid];
    if (tid < 64) { s_neg[tid] = (mask2[b * 64 + tid] > 0.f) ? 0.f : -1e9f; s_bg[tid] = bg[m * 64 + tid]; }
    if (tid < 96) {
        int row = (tid >> 5) * 256 + m * 32 + (tid & 31);
        s_bih[tid] = bih[row]; s_bhh[tid] = bhh[row];
    }
    if (tid < 32) s_hf[tid] = 0.f;

    // persistent register weights: wih K-high (pairs 128..255)
    uint4 wiA = {}, wiB = {}, wiC = {}, wiD = {};
    const int oAD = ((tid >> 6) << 3) + ((tid & 63) >> 3);   // wave*8 + (l>>3)
    const int ksAD = tid & 7;
    if (tid < 768) {
        const uint4* wip = (const uint4*)(wsrc + WIHP_O + m * 24576 + oAD * 256 + 128 + ksAD * 16);
        wiA = wip[0]; wiB = wip[1]; wiC = wip[2]; wiD = wip[3];
    }

    u64* exch64 = (u64*)(ws + EXCH_B) + (size_t)b * 1024;
    const u32* g_projx = (const u32*)(ws + PROJX_B);
    const u32* g_gatex = (const u32*)(ws + GATEX_B);

    int dead = 0;
    __syncthreads();

    for (int t = 0; t < 256; ++t) {
        const u32 st = (u32)(t + 1);
        // ---- issue prefetch loads (lanes 896+) ----
        float4 xv = {};
        u32 pxv = 0, gxv = 0; float mkv = 0.f;
        if (tid >= 896 && tid < 912) {
            if (m < 4)
                xv = ((const float4*)(seq1 + (size_t)(b * 256 + t) * 256 + m * 64))[tid - 896];
        } else if (tid >= 912 && tid < 976)
            pxv = g_projx[(b * 256 + t) * 64 + (tid - 912)];
        else if (tid >= 976 && tid < 1008)
            gxv = g_gatex[(b * 256 + t) * 256 + m * 32 + (tid - 976)];
        else if (tid == 1008)
            mkv = mask1[b * 256 + t];

        // ---- poll {php pairs, h pairs} from prev step (stamp == t) ----
        if (t > 0) {
            u64 w1 = 0, w2 = 0;
            const bool q1 = tid < 512, q2 = tid < 128;
            const u32 stp = (u32)t;
            if (!dead) {
                int sp = 0;
                for (;;) {
                    w1 = q1 ? aload64(exch64 + tid) : 0;
                    w2 = q2 ? aload64(exch64 + 512 + tid) : 0;
                    bool ok1 = !q1 || (((((u32)w1) >> 16) == stp) && ((((u32)(w1 >> 32)) >> 16) == stp));
                    bool ok2 = !q2 || (((((u32)w2) >> 16) == stp) && ((((u32)(w2 >> 32)) >> 16) == stp));
                    if (__all((int)(ok1 && ok2))) break;
                    __builtin_amdgcn_s_sleep(1);
                    if (++sp > (1 << 17)) { dead = 1; break; }
                }
            } else {
                w1 = q1 ? aload64(exch64 + tid) : 0;
                w2 = q2 ? aload64(exch64 + 512 + tid) : 0;
            }
            if (q1) {
                // pair (p0, p0+1), 8 member-partials in 8 consecutive lanes
                float a0 = f16low((u32)w1), a1 = f16low((u32)(w1 >> 32));
                a0 += __shfl_down(a0, 4, 8); a0 += __shfl_down(a0, 2, 8); a0 += __shfl_down(a0, 1, 8);
                a1 += __shfl_down(a1, 4, 8); a1 += __shfl_down(a1, 2, 8); a1 += __shfl_down(a1, 1, 8);
                if ((tid & 7) == 0) {
                    int p0 = (tid >> 3) * 2;
                    int base = p0 + (p0 >> 3);
                    s_projh[base] = a0; s_projh[base + 1] = a1;
                }
            }
            if (q2) {
                u32 val = (((u32)w2) & 0xFFFFu) | ((((u32)(w2 >> 32)) & 0xFFFFu) << 16);
                s_h2u[(tid >> 4) * 20 + (tid & 15)] = val;
            }
        } else {
            if (tid < 160) s_h2u[tid] = 0u;
            if (tid < 144) s_projh[tid] = 0.f;
        }
        // ---- prefetch stores (same phase, after per-wave poll exit) ----
        if (tid >= 896 && tid < 912) {
            int q = tid - 896;
            s_xc[4 * q] = xv.x; s_xc[4 * q + 1] = xv.y; s_xc[4 * q + 2] = xv.z; s_xc[4 * q + 3] = xv.w;
        } else if (tid >= 912 && tid < 976) {
            half2_v h = h2_of(pxv); int i = tid - 912;
            int base = 2 * i + (i >> 2);
            s_projx[base] = (float)h[0]; s_projx[base + 1] = (float)h[1];
        } else if (tid >= 976 && tid < 1008) {
            half2_v h = h2_of(gxv); int i = tid - 976;
            s_gx[2 * i] = (float)h[0]; s_gx[2 * i + 1] = (float)h[1];
        } else if (tid == 1008) s_m1v[0] = mkv;
        __syncthreads();                                    // sync 1

        // ---- B: scores (all lanes; 16-lane rows; padded conflict-free reads) ----
        {
            int j = tid >> 4, pk = tid & 15, p0 = pk * 8, pb = pk * 9;
            uint4 sv = *(const uint4*)&s_s2p[j * 144 + p0];
            const u32* su = (const u32*)&sv;
            float acc = 0.f;
            #pragma unroll
            for (int q = 0; q < 4; ++q) {
                half2_v h = h2_of(su[q]);
                int pc = pb + 2 * q;
                float a0 = (float)h[0] + s_projx[pc] + s_projh[pc];
                float a1 = (float)h[1] + s_projx[pc + 1] + s_projh[pc + 1];
                acc += fast_tanh(a0) * s_v[pc];
                acc += fast_tanh(a1) * s_v[pc + 1];
            }
            acc += __shfl_down(acc, 8, 16);
            acc += __shfl_down(acc, 4, 16);
            acc += __shfl_down(acc, 2, 16);
            acc += __shfl_down(acc, 1, 16);
            if (pk == 0) s_w[j] = acc + s_neg[j];
        }
        __syncthreads();                                    // sync 2
        // ---- softmax (64 lanes) + pack to f16 pairs ----
        if (tid < 64) {
            float sc = s_w[tid], mx = sc;
            #pragma unroll
            for (int off = 32; off > 0; off >>= 1) mx = fmaxf(mx, __shfl_xor(mx, off));
            float e = __expf(sc - mx), s = e;
            #pragma unroll
            for (int off = 32; off > 0; off >>= 1) s += __shfl_xor(s, off);
            float wv = e / s;
            float nb = __shfl_down(wv, 1);
            if (!(tid & 1)) s_wp[tid >> 1] = pack_h2(wv, nb);
        }
        __syncthreads();                                    // sync 3

        // ---- C' fused: 8-lane group per o; lanes 0-3 gate(M1), 4-7 att(s2T); packed-w fdot2 ----
        if (tid < 512) {
            int o = tid >> 3, r = tid & 7, q = r & 3;
            const u32* src = (r >= 4) ? &s_s2Tu[o * 33] : &s_m1u[o * 33];
            float acc = 0.f;
            #pragma unroll
            for (int c = 0; c < 8; ++c)
                acc = fdot2(h2_of(src[q * 8 + c]), h2_of(s_wp[q * 8 + c]), acc);
            acc += __shfl_down(acc, 2, 4);
            acc += __shfl_down(acc, 1, 4);
            float attv = __shfl_down(acc, 4, 8);   // lane r=0 gets lane r=4's att sum
            float fval = 0.f;
            if (r == 0) {
                float g = acc + s_gx[o] + s_bg[o];
                float inpv = (m < 4) ? s_xc[o] : attv;
                fval = fast_sigmoid(g) * inpv;
            }
            float fpn = __shfl_down(fval, 8, 16);  // lane (tid&15)==0 gets odd-o value
            if ((tid & 15) == 0)
                astore64(&exch64[640 + m * 32 + (tid >> 4)], mkw64(fval, fpn, st));
        }
        // ---- phase A: gh partials (in the ip-RTT shadow; threads 0..767) ----
        if (tid < 768) {
            const uint4* wbase = (const uint4*)s_whh4 + (tid >> 6) * 256;
            float acc = 0.f;
            #pragma unroll
            for (int c = 0; c < 4; ++c) {
                uint4 wv4 = wbase[c * 64 + (tid & 63)];
                uint4 av = *(const uint4*)&s_h2u[ksAD * 20 + c * 4];
                acc = dot4(wv4, av, acc);
            }
            acc += __shfl_down(acc, 4, 8);
            acc += __shfl_down(acc, 2, 8);
            acc += __shfl_down(acc, 1, 8);
            if (ksAD == 0) s_redA[oAD] = acc + s_bhh[oAD];
        }
        // ---- poll ip (256 u64 words, stamp == st) ----
        if (tid < 256) {
            u64 wv;
            if (!dead) {
                int sp = 0;
                for (;;) {
                    wv = aload64(exch64 + 640 + tid);
                    bool ok = ((((u32)wv) >> 16) == st) && ((((u32)(wv >> 32)) >> 16) == st);
                    if (__all((int)ok)) break;
                    __builtin_amdgcn_s_sleep(1);
                    if (++sp > (1 << 17)) { dead = 1; break; }
                }
            } else wv = aload64(exch64 + 640 + tid);
            u32 val = (((u32)wv) & 0xFFFFu) | ((((u32)(wv >> 32)) & 0xFFFFu) << 16);
            if (tid < 128) s_ip2a[(tid >> 4) * 20 + (tid & 15)] = val;
            else { int j = tid - 128; s_ip2b[(j >> 4) * 20 + (j & 15)] = val; }
        }
        __syncthreads();                                    // sync 4

        // ---- phase D: gi partials (shfl-reduced, bias folded) ----
        if (tid < 768) {
            const uint4* wbase = (const uint4*)s_wih4 + (tid >> 6) * 256;
            float acc = 0.f;
            #pragma unroll
            for (int c = 0; c < 4; ++c) {
                uint4 wv4 = wbase[c * 64 + (tid & 63)];
                uint4 av = *(const uint4*)&s_ip2a[ksAD * 20 + c * 4];
                acc = dot4(wv4, av, acc);
            }
            acc = dot4(wiA, *(const uint4*)&s_ip2b[ksAD * 20 + 0],  acc);
            acc = dot4(wiB, *(const uint4*)&s_ip2b[ksAD * 20 + 4],  acc);
            acc = dot4(wiC, *(const uint4*)&s_ip2b[ksAD * 20 + 8],  acc);
            acc = dot4(wiD, *(const uint4*)&s_ip2b[ksAD * 20 + 12], acc);
            acc += __shfl_down(acc, 4, 8);
            acc += __shfl_down(acc, 2, 8);
            acc += __shfl_down(acc, 1, 8);
            if (ksAD == 0) s_redD[oAD] = acc + s_bih[oAD];
        }
        __syncthreads();                                    // sync 5

        // ---- GRU elementwise + h publish (u64 pairs) ----
        if (tid < 32) {
            int o = tid;
            float r_ = fast_sigmoid(s_redD[o] + s_redA[o]);
            float z_ = fast_sigmoid(s_redD[32 + o] + s_redA[32 + o]);
            float n_ = fast_tanh(s_redD[64 + o] + r_ * s_redA[64 + o]);
            float hn = (1.f - z_) * n_ + z_ * s_hf[o];
            s_hf[o] = hn;
            out[(size_t)(b * 256 + t) * 256 + m * 32 + o] = hn * s_m1v[0];
            float nb = __shfl_down(hn, 1);
            if (!(o & 1)) {
                s_hloc[o >> 1] = pack_h2(hn, nb);
                astore64(&exch64[512 + m * 16 + (o >> 1)], mkw64(hn, nb, st));
            }
        }
        __syncthreads();                                    // sync 6

        // ---- php pair partials from own new h-slice, publish u64 [p-pair][mm] ----
        if (tid < 512) {
            int p2 = tid >> 3, r = tid & 7;
            int p0 = 2 * p2, u0 = 2 * r;
            float a0 = 0.f, a1 = 0.f;
            #pragma unroll
            for (int cc = 0; cc < 2; ++cc) {
                u32 hp = s_hloc[u0 + cc];
                a0 = fdot2(h2_of(s_w2k[p0 * 17 + u0 + cc]), h2_of(hp), a0);
                a1 = fdot2(h2_of(s_w2k[(p0 + 1) * 17 + u0 + cc]), h2_of(hp), a1);
            }
            a0 += __shfl_down(a0, 4, 8); a0 += __shfl_down(a0, 2, 8); a0 += __shfl_down(a0, 1, 8);
            a1 += __shfl_down(a1, 4, 8); a1 += __shfl_down(a1, 2, 8); a1 += __shfl_down(a1, 1, 8);
            if (r == 0) astore64(&exch64[p2 * 8 + m], mkw64(a0, a1, st));
        }
        // no trailing sync: next-iteration polls gate on stamps
    }
}

extern "C" void kernel_launch(void* const* d_in, const int* in_sizes, int n_in,
                              void* d_out, int out_size, void* d_ws, size_t ws_size,
                              hipStream_t stream) {
    const float* seq1  = (const float*)d_in[0];
    const float* seq2  = (const float*)d_in[1];
    const float* mask1 = (const float*)d_in[2];
    const float* mask2 = (const float*)d_in[3];
    const float* W1    = (const float*)d_in[4];
    const float* W2    = (const float*)d_in[5];
    const float* v     = (const float*)d_in[6];
    const float* Wg    = (const float*)d_in[7];
    const float* bg    = (const float*)d_in[8];
    const float* wih   = (const float*)d_in[9];
    const float* whh   = (const float*)d_in[10];
    const float* bih   = (const float*)d_in[11];
    const float* bhh   = (const float*)d_in[12];

    char* ws = (char*)d_ws;

    (void)hipFuncSetAttribute(reinterpret_cast<const void*>(match_rnn),
                              hipFuncAttributeMaxDynamicSharedMemorySize, SMEM_BYTES);

    prep_pack_w<<<dim3((NPACKW + 255) / 256), dim3(256), 0, stream>>>(W2, wih, whh, (u32*)ws);
    prep_s2p<<<dim3(1024), dim3(256), 0, stream>>>(seq2, W1, (_Float16*)(ws + S2P_B));
    prep_s2T<<<dim3(2048), dim3(256), 0, stream>>>(seq2, (_Float16*)(ws + S2T_B));
    prep_m1<<<dim3(4096), dim3(256), 0, stream>>>(Wg, seq2, (_Float16*)(ws + M1_B));
    prep_gemm<<<dim3(128, 2), dim3(256), 0, stream>>>(seq1, W2, 0, (_Float16*)(ws + PROJX_B), 128);
    prep_gemm<<<dim3(128, 8), dim3(256), 0, stream>>>(seq1, Wg, 1, (_Float16*)(ws + GATEX_B), 512);
    (void)hipMemsetAsync(ws + EXCH_B, 0, 262144, stream);
    match_rnn<<<dim3(256), dim3(1024), SMEM_BYTES, stream>>>(seq1, mask1, mask2, v, bg, bih, bhh, ws, (float*)d_out);
}